// Round 13
// baseline (253.165 us; speedup 1.0000x reference)
//
#include <hip/hip_runtime.h>

#define HDIM 128
#define VOCAB 800
#define FB 32
#define NB 64
#define TILE 1024
#define TILE_N 512

typedef float f4 __attribute__((ext_vector_type(4)));
typedef float f2 __attribute__((ext_vector_type(2)));

// accumulate 8 bf16 (uint4 h) into two float4s
#define ACC8(pa, pb, h) { \
    pa.x += __uint_as_float(h.x << 16); \
    pa.y += __uint_as_float(h.x & 0xffff0000u); \
    pa.z += __uint_as_float(h.y << 16); \
    pa.w += __uint_as_float(h.y & 0xffff0000u); \
    pb.x += __uint_as_float(h.z << 16); \
    pb.y += __uint_as_float(h.z & 0xffff0000u); \
    pb.z += __uint_as_float(h.w << 16); \
    pb.w += __uint_as_float(h.w & 0xffff0000u); }

static __device__ __forceinline__ unsigned short f2bf(float f) {
    unsigned int u = __float_as_uint(f);
    return (unsigned short)((u + 0x7fffu + ((u >> 16) & 1u)) >> 16);
}

// ---------- mega streaming kernel (nt loads; 2 rows/wave argmax; 4-load cvt):
// [0,6250) argmax x2 | [6250,6641) edge counts | [6641,12891) x->bf16 | [12891,13292) prep
__global__ void k_amc(const float* __restrict__ frags, int* __restrict__ frag_id,
                      const float* __restrict__ x, unsigned short* __restrict__ xb,
                      const int* __restrict__ row, const int* __restrict__ col,
                      int* __restrict__ cnt,
                      const float* __restrict__ emb, const float* __restrict__ W_f,
                      const float* __restrict__ W_s, const float* __restrict__ b_f,
                      const float* __restrict__ b_s, float* __restrict__ E2,
                      float* __restrict__ bfs, int F) {
    __shared__ float e[2][HDIM], t1[2][HDIM];
    int b = blockIdx.x, t = threadIdx.x;
    if (b < 6250) {
        int wave = (b * 4 + (t >> 6)) * 2;         // rows wave, wave+1
        int lane = t & 63;
        const f4* r0 = reinterpret_cast<const f4*>(frags + (size_t)wave * VOCAB);
        const f4* r1 = reinterpret_cast<const f4*>(frags + (size_t)(wave + 1) * VOCAB);
        float b0 = -1e30f, b1 = -1e30f;
        int i0 = 0, i1 = 0;
        for (int i = lane; i < VOCAB / 4; i += 64) {
            f4 v0 = __builtin_nontemporal_load(r0 + i);
            f4 v1 = __builtin_nontemporal_load(r1 + i);
            int base = i * 4;
            if (v0.x > b0) { b0 = v0.x; i0 = base + 0; }
            if (v0.y > b0) { b0 = v0.y; i0 = base + 1; }
            if (v0.z > b0) { b0 = v0.z; i0 = base + 2; }
            if (v0.w > b0) { b0 = v0.w; i0 = base + 3; }
            if (v1.x > b1) { b1 = v1.x; i1 = base + 0; }
            if (v1.y > b1) { b1 = v1.y; i1 = base + 1; }
            if (v1.z > b1) { b1 = v1.z; i1 = base + 2; }
            if (v1.w > b1) { b1 = v1.w; i1 = base + 3; }
        }
        for (int off = 32; off > 0; off >>= 1) {
            float o0 = __shfl_xor(b0, off, 64);
            int   x0 = __shfl_xor(i0, off, 64);
            float o1 = __shfl_xor(b1, off, 64);
            int   x1 = __shfl_xor(i1, off, 64);
            if (o0 > b0 || (o0 == b0 && x0 < i0)) { b0 = o0; i0 = x0; }
            if (o1 > b1 || (o1 == b1 && x1 < i1)) { b1 = o1; i1 = x1; }
        }
        if (lane == 0) {
            frag_id[wave] = i0;
            frag_id[wave + 1] = i1;
        }
    } else if (b < 6641) {
        int i = (b - 6250) * 256 + t;
        if (i < 100000) {
            int4 r4 = reinterpret_cast<const int4*>(row)[i];
            int4 c4 = reinterpret_cast<const int4*>(col)[i];
            atomicAdd(&cnt[F + r4.x], 1); atomicAdd(&cnt[F + r4.y], 1);
            atomicAdd(&cnt[F + r4.z], 1); atomicAdd(&cnt[F + r4.w], 1);
            atomicAdd(&cnt[c4.x], 1); atomicAdd(&cnt[c4.y], 1);
            atomicAdd(&cnt[c4.z], 1); atomicAdd(&cnt[c4.w], 1);
        }
    } else if (b < 12891) {
        size_t i = (size_t)(b - 6641) * 256 + t;   // 16 floats per thread
        const f4* xp = reinterpret_cast<const f4*>(x);
        f4 v0 = __builtin_nontemporal_load(xp + 4 * i);
        f4 v1 = __builtin_nontemporal_load(xp + 4 * i + 1);
        f4 v2 = __builtin_nontemporal_load(xp + 4 * i + 2);
        f4 v3 = __builtin_nontemporal_load(xp + 4 * i + 3);
        uint4 o0, o1;
        o0.x = (unsigned)f2bf(v0.x) | ((unsigned)f2bf(v0.y) << 16);
        o0.y = (unsigned)f2bf(v0.z) | ((unsigned)f2bf(v0.w) << 16);
        o0.z = (unsigned)f2bf(v1.x) | ((unsigned)f2bf(v1.y) << 16);
        o0.w = (unsigned)f2bf(v1.z) | ((unsigned)f2bf(v1.w) << 16);
        o1.x = (unsigned)f2bf(v2.x) | ((unsigned)f2bf(v2.y) << 16);
        o1.y = (unsigned)f2bf(v2.z) | ((unsigned)f2bf(v2.w) << 16);
        o1.z = (unsigned)f2bf(v3.x) | ((unsigned)f2bf(v3.y) << 16);
        o1.w = (unsigned)f2bf(v3.z) | ((unsigned)f2bf(v3.w) << 16);
        reinterpret_cast<uint4*>(xb + i * 16)[0] = o0;
        reinterpret_cast<uint4*>(xb + i * 16)[1] = o1;
    } else {
        int bp = b - 12891;
        int j = t & 127, half = t >> 7;
        if (bp < 400) {
            int v = bp * 2 + half;
            e[half][j] = emb[(size_t)v * HDIM + j];
            __syncthreads();
            float a = 0.f;
            for (int k = 0; k < HDIM; ++k)
                a = fmaf(e[half][k], W_f[k * HDIM + j], a);
            t1[half][j] = a;
            __syncthreads();
            float bb = 0.f;
            for (int k = 0; k < HDIM; ++k)
                bb = fmaf(t1[half][k], W_s[(HDIM + k) * HDIM + j], bb);
            E2[(size_t)v * HDIM + j] = bb;
        } else {
            if (half == 0) e[0][j] = b_f[j];
            __syncthreads();
            if (half == 0) {
                float bb = b_s[j];
                for (int k = 0; k < HDIM; ++k)
                    bb = fmaf(e[0][k], W_s[(HDIM + k) * HDIM + j], bb);
                bfs[j] = bb;
            }
        }
    }
}

// ---------- per-256-block sums over concatenated cnt (L = F+N)
__global__ void k_bsum(const int* __restrict__ cnt, int L, int* __restrict__ bsum) {
    __shared__ int s[256];
    int t = threadIdx.x;
    int i = blockIdx.x * 256 + t;
    s[t] = (i < L) ? cnt[i] : 0;
    __syncthreads();
    for (int o = 128; o > 0; o >>= 1) {
        if (t < o) s[t] += s[t + o];
        __syncthreads();
    }
    if (t == 0) bsum[blockIdx.x] = s[0];
}

// ---------- exclusive scan of block sums (nb <= 1024), single block
__global__ void k_scan(int* __restrict__ bsum, int nb) {
    __shared__ int s[1024];
    int t = threadIdx.x;
    int v = (t < nb) ? bsum[t] : 0;
    s[t] = v;
    __syncthreads();
    for (int o = 1; o < 1024; o <<= 1) {
        int a = (t >= o) ? s[t - o] : 0;
        __syncthreads();
        s[t] += a;
        __syncthreads();
    }
    if (t < nb) bsum[t] = s[t] - v;
}

// ---------- base[i] = bsum[block] + in-block exclusive scan
__global__ void k_base(const int* __restrict__ cnt, const int* __restrict__ bsum, int L,
                       int* __restrict__ base) {
    __shared__ int s[256];
    int t = threadIdx.x;
    int i = blockIdx.x * 256 + t;
    int v = (i < L) ? cnt[i] : 0;
    s[t] = v;
    __syncthreads();
    for (int o = 1; o < 256; o <<= 1) {
        int a = (t >= o) ? s[t - o] : 0;
        __syncthreads();
        s[t] += a;
        __syncthreads();
    }
    if (i < L) base[i] = bsum[blockIdx.x] + s[t] - v;
}

// ---------- place edges into concatenated CSR; cursor IS base
__global__ void k_place(const int* __restrict__ row, const int* __restrict__ col,
                        int* __restrict__ base, int* __restrict__ pay, int F, int E) {
    int i = blockIdx.x * 256 + threadIdx.x;
    if (i >= E / 4) return;
    int4 r4 = reinterpret_cast<const int4*>(row)[i];
    int4 c4 = reinterpret_cast<const int4*>(col)[i];
#define PL(r, c) { \
    int pc = atomicAdd(&base[c], 1); pay[pc] = r; \
    int pr = atomicAdd(&base[F + r], 1); pay[pr] = c; }
    PL(r4.x, c4.x) PL(r4.y, c4.y) PL(r4.z, c4.z) PL(r4.w, c4.w)
#undef PL
}

// ---------- fragment pool (bf16 xb gather, uint4/16-lane rows, 3-deep) + packed matvec
__global__ __launch_bounds__(256) void k_frag(
        const unsigned short* __restrict__ xb, const int* __restrict__ base,
        const int* __restrict__ pay, const int* __restrict__ frag_id,
        const float* __restrict__ W_s, const float* __restrict__ E2,
        const float* __restrict__ bfs, unsigned short* __restrict__ fembb, int F, int E) {
    __shared__ f2 sI[FB / 2][HDIM];   // fragment PAIRS interleaved
    __shared__ int eidx[TILE];
    __shared__ int cb[FB + 1];
    int t = threadIdx.x;
    int sg = t >> 4, l = t & 15;      // 16 sub-groups x 16 lanes; lane covers dims 8l..8l+7
    int fb = blockIdx.x * FB;
    if (t <= FB) {
        int idx = fb + t - 1;
        cb[t] = (idx < 0) ? 0 : ((idx < F) ? base[idx] : E);
    }
    __syncthreads();
    int st0 = cb[sg],      d0 = cb[sg + 1] - st0;
    int st1 = cb[16 + sg], d1 = cb[17 + sg] - st1;
    int p0 = cb[0], pend = cb[FB];
    const uint4* x4 = reinterpret_cast<const uint4*>(xb);   // row = 16 uint4
    float4 z = make_float4(0.f, 0.f, 0.f, 0.f);
    float4 a0A0 = z, a0A1 = z, a0B0 = z, a0B1 = z, a0C0 = z, a0C1 = z;
    float4 a1A0 = z, a1A1 = z, a1B0 = z, a1B1 = z, a1C0 = z, a1C1 = z;
    for (int tb = p0; tb < pend; tb += TILE) {
        int nload = min(TILE, pend - tb);
        for (int i = t; i < nload; i += 256) eidx[i] = pay[tb + i];
        __syncthreads();
        int lim = tb + nload;
        int lo0 = max(st0, tb) - tb, hi0 = min(st0 + d0, lim) - tb;
        int lo1 = max(st1, tb) - tb, hi1 = min(st1 + d1, lim) - tb;
        int m = max(hi0 - lo0, hi1 - lo1);
        for (int j = 0; j < m; j += 3) {
            if (lo0 + j < hi0)     { uint4 h = x4[(size_t)eidx[lo0 + j]     * 16 + l]; ACC8(a0A0, a0A1, h); }
            if (lo0 + j + 1 < hi0) { uint4 h = x4[(size_t)eidx[lo0 + j + 1] * 16 + l]; ACC8(a0B0, a0B1, h); }
            if (lo0 + j + 2 < hi0) { uint4 h = x4[(size_t)eidx[lo0 + j + 2] * 16 + l]; ACC8(a0C0, a0C1, h); }
            if (lo1 + j < hi1)     { uint4 h = x4[(size_t)eidx[lo1 + j]     * 16 + l]; ACC8(a1A0, a1A1, h); }
            if (lo1 + j + 1 < hi1) { uint4 h = x4[(size_t)eidx[lo1 + j + 1] * 16 + l]; ACC8(a1B0, a1B1, h); }
            if (lo1 + j + 2 < hi1) { uint4 h = x4[(size_t)eidx[lo1 + j + 2] * 16 + l]; ACC8(a1C0, a1C1, h); }
        }
        __syncthreads();
    }
    {
        float inv0 = 1.0f / fmaxf((float)d0, 1.0f);
        float inv1 = 1.0f / fmaxf((float)d1, 1.0f);
        int pr0 = sg >> 1, pa0 = sg & 1;
        int pr1 = (16 + sg) >> 1, pa1 = sg & 1;
        float v0[8] = { (a0A0.x + a0B0.x + a0C0.x) * inv0, (a0A0.y + a0B0.y + a0C0.y) * inv0,
                        (a0A0.z + a0B0.z + a0C0.z) * inv0, (a0A0.w + a0B0.w + a0C0.w) * inv0,
                        (a0A1.x + a0B1.x + a0C1.x) * inv0, (a0A1.y + a0B1.y + a0C1.y) * inv0,
                        (a0A1.z + a0B1.z + a0C1.z) * inv0, (a0A1.w + a0B1.w + a0C1.w) * inv0 };
        float v1[8] = { (a1A0.x + a1B0.x + a1C0.x) * inv1, (a1A0.y + a1B0.y + a1C0.y) * inv1,
                        (a1A0.z + a1B0.z + a1C0.z) * inv1, (a1A0.w + a1B0.w + a1C0.w) * inv1,
                        (a1A1.x + a1B1.x + a1C1.x) * inv1, (a1A1.y + a1B1.y + a1C1.y) * inv1,
                        (a1A1.z + a1B1.z + a1C1.z) * inv1, (a1A1.w + a1B1.w + a1C1.w) * inv1 };
#pragma unroll
        for (int i = 0; i < 8; ++i) {
            ((float*)&sI[pr0][8 * l + i])[pa0] = v0[i];
            ((float*)&sI[pr1][8 * l + i])[pa1] = v1[i];
        }
    }
    __syncthreads();
    // matvec: thread = dim d; half fh handles 8 fragment-pairs (16 frags)
    int d = t & 127;
    int fh = t >> 7;
    float bv = bfs[d];
    f2 acc2[8];
#pragma unroll
    for (int q = 0; q < 8; ++q) {
        int pr = fh * 8 + q;
        int fA = fb + 2 * pr, fB = fA + 1;
        int idA = frag_id[min(fA, F - 1)];
        int idB = frag_id[min(fB, F - 1)];
        acc2[q].x = E2[(size_t)idA * HDIM + d] + bv;
        acc2[q].y = E2[(size_t)idB * HDIM + d] + bv;
    }
    for (int k = 0; k < HDIM; k += 2) {
        float w0 = W_s[(k + 0) * HDIM + d];
        float w1 = W_s[(k + 1) * HDIM + d];
        f2 w0v; w0v.x = w0; w0v.y = w0;
        f2 w1v; w1v.x = w1; w1v.y = w1;
#pragma unroll
        for (int q = 0; q < 8; ++q) {
            int pr = fh * 8 + q;
            f2 vv0 = sI[pr][k];
            f2 vv1 = sI[pr][k + 1];
            acc2[q] += vv0 * w0v + vv1 * w1v;
        }
    }
#pragma unroll
    for (int q = 0; q < 8; ++q) {
        int pr = fh * 8 + q;
        int fA = fb + 2 * pr;
        if (fA < F)     fembb[(size_t)fA * HDIM + d]       = f2bf(acc2[q].x);
        if (fA + 1 < F) fembb[(size_t)(fA + 1) * HDIM + d] = f2bf(acc2[q].y);
    }
}

// ---------- node pool + divide; bf16 femb gather (uint4/16-lane rows), nt out stores
__global__ __launch_bounds__(256) void k_node(
        const unsigned short* __restrict__ fembb, const int* __restrict__ base,
        const int* __restrict__ pay, float* __restrict__ out, int F, int E, int N) {
    __shared__ int eidx[TILE_N];
    __shared__ int cb[NB + 1];
    int t = threadIdx.x;
    int sg = t >> 4, l = t & 15;      // 16 sub-groups; lane covers dims 8l..8l+7
    int n0 = blockIdx.x * NB;
    if (t <= NB) {
        int idx = n0 + t - 1;
        cb[t] = (idx < 0) ? E : base[F + idx];   // row region starts at E in pay
    }
    __syncthreads();
    int st_[4], dg_[4];
    float4 z = make_float4(0.f, 0.f, 0.f, 0.f);
    float4 aA0[4] = {z, z, z, z}, aA1[4] = {z, z, z, z};
    float4 aB0[4] = {z, z, z, z}, aB1[4] = {z, z, z, z};
#pragma unroll
    for (int q = 0; q < 4; ++q) {
        st_[q] = cb[sg * 4 + q];
        dg_[q] = cb[sg * 4 + q + 1] - st_[q];
    }
    int p0 = cb[0], pend = cb[NB];
    const uint4* f4p = reinterpret_cast<const uint4*>(fembb);
    for (int tb = p0; tb < pend; tb += TILE_N) {
        int nload = min(TILE_N, pend - tb);
        for (int i = t; i < nload; i += 256) eidx[i] = pay[tb + i];
        __syncthreads();
        int lim = tb + nload;
        int lo[4], hi[4];
        int m = 0;
#pragma unroll
        for (int q = 0; q < 4; ++q) {
            lo[q] = max(st_[q], tb) - tb;
            hi[q] = min(st_[q] + dg_[q], lim) - tb;
            m = max(m, hi[q] - lo[q]);
        }
        for (int j = 0; j < m; j += 2) {
#pragma unroll
            for (int q = 0; q < 4; ++q) {
                if (lo[q] + j < hi[q])     { uint4 h = f4p[(size_t)eidx[lo[q] + j]     * 16 + l]; ACC8(aA0[q], aA1[q], h); }
                if (lo[q] + j + 1 < hi[q]) { uint4 h = f4p[(size_t)eidx[lo[q] + j + 1] * 16 + l]; ACC8(aB0[q], aB1[q], h); }
            }
        }
        __syncthreads();
    }
    f4* o4 = reinterpret_cast<f4*>(out);
#pragma unroll
    for (int q = 0; q < 4; ++q) {
        float inv = 1.0f / fmaxf((float)dg_[q], 1.0f);
        f4 w0, w1;
        w0.x = (aA0[q].x + aB0[q].x) * inv; w0.y = (aA0[q].y + aB0[q].y) * inv;
        w0.z = (aA0[q].z + aB0[q].z) * inv; w0.w = (aA0[q].w + aB0[q].w) * inv;
        w1.x = (aA1[q].x + aB1[q].x) * inv; w1.y = (aA1[q].y + aB1[q].y) * inv;
        w1.z = (aA1[q].z + aB1[q].z) * inv; w1.w = (aA1[q].w + aB1[q].w) * inv;
        size_t nrow = (size_t)(n0 + sg * 4 + q) * 32;
        __builtin_nontemporal_store(w0, o4 + nrow + 2 * l + 0);
        __builtin_nontemporal_store(w1, o4 + nrow + 2 * l + 1);
    }
}

extern "C" void kernel_launch(void* const* d_in, const int* in_sizes, int n_in,
                              void* d_out, int out_size, void* d_ws, size_t ws_size,
                              hipStream_t stream) {
    const float* x         = (const float*)d_in[0];
    const float* fragments = (const float*)d_in[1];
    const float* emb_table = (const float*)d_in[2];
    const float* W_f       = (const float*)d_in[3];
    const float* b_f       = (const float*)d_in[4];
    const float* W_s       = (const float*)d_in[5];
    const float* b_s       = (const float*)d_in[6];
    const int*   row       = (const int*)d_in[7];
    const int*   col       = (const int*)d_in[8];
    float* out = (float*)d_out;

    const int N = 200000, F = 50000, E = 400000;
    const int L = F + N;                 // concatenated CSR domain
    const int NBT = (L + 255) / 256;     // 977

    // xb (bf16 x, 51.2 MB) lives in d_out: fully dead before k_node overwrites out.
    unsigned short* xb = (unsigned short*)d_out;

    unsigned short* fembb = (unsigned short*)d_ws;     // F*128 bf16 = 12.8 MB
    int* cnt     = (int*)(fembb + (size_t)F * HDIM);   // L   (cols at 0, rows at F)
    int* base    = cnt + L;                            // L
    int* bsum    = base + L;                           // 1024
    int* pay     = bsum + 1024;                        // 2E  (col CSR at 0, row CSR at E)
    int* frag_id = pay + 2 * E;                        // F
    float* E2    = (float*)(frag_id + F);              // VOCAB*128
    float* bfs   = E2 + VOCAB * HDIM;                  // 128

    hipMemsetAsync(cnt, 0, (size_t)L * sizeof(int), stream);

    k_amc<<<13292, 256, 0, stream>>>(fragments, frag_id, x, xb, row, col, cnt,
                                     emb_table, W_f, W_s, b_f, b_s, E2, bfs, F);
    k_bsum<<<NBT, 256, 0, stream>>>(cnt, L, bsum);
    k_scan<<<1, 1024, 0, stream>>>(bsum, NBT);
    k_base<<<NBT, 256, 0, stream>>>(cnt, bsum, L, base);
    k_place<<<(E / 4 + 255) / 256, 256, 0, stream>>>(row, col, base, pay, F, E);
    k_frag<<<(F + FB - 1) / FB, 256, 0, stream>>>(xb, base, pay, frag_id, W_s, E2, bfs,
                                                  fembb, F, E);
    k_node<<<N / NB, 256, 0, stream>>>(fembb, base, pay, out, F, E, N);
}

// Round 14
// 239.696 us; speedup vs baseline: 1.0562x; 1.0562x over previous
//
#include <hip/hip_runtime.h>

#define HDIM 128
#define VOCAB 800
#define FB 32
#define NB 64
#define TILE 1024
#define TILE_N 512

typedef float f4 __attribute__((ext_vector_type(4)));
typedef float f2 __attribute__((ext_vector_type(2)));

// accumulate 8 bf16 (uint4 h) into two float4s
#define ACC8(pa, pb, h) { \
    pa.x += __uint_as_float(h.x << 16); \
    pa.y += __uint_as_float(h.x & 0xffff0000u); \
    pa.z += __uint_as_float(h.y << 16); \
    pa.w += __uint_as_float(h.y & 0xffff0000u); \
    pb.x += __uint_as_float(h.z << 16); \
    pb.y += __uint_as_float(h.z & 0xffff0000u); \
    pb.z += __uint_as_float(h.w << 16); \
    pb.w += __uint_as_float(h.w & 0xffff0000u); }

static __device__ __forceinline__ unsigned short f2bf(float f) {
    unsigned int u = __float_as_uint(f);
    return (unsigned short)((u + 0x7fffu + ((u >> 16) & 1u)) >> 16);
}

// ---------- mega streaming kernel, STRIPED block types:
// physical even b<25000 -> argmax, odd -> cvt (concurrent read + read/write streams);
// [25000,25391) -> edge counts; [25391,25792) -> prep
__global__ void k_amc(const float* __restrict__ frags, int* __restrict__ frag_id,
                      const float* __restrict__ x, unsigned short* __restrict__ xb,
                      const int* __restrict__ row, const int* __restrict__ col,
                      int* __restrict__ cnt,
                      const float* __restrict__ emb, const float* __restrict__ W_f,
                      const float* __restrict__ W_s, const float* __restrict__ b_f,
                      const float* __restrict__ b_s, float* __restrict__ E2,
                      float* __restrict__ bfs, int F) {
    __shared__ float e[2][HDIM], t1[2][HDIM];
    int bb = blockIdx.x, t = threadIdx.x;
    if (bb < 25000) {
        if ((bb & 1) == 0) {
            // ---- argmax block (logical 0..12499)
            int blk = bb >> 1;
            int wave = blk * 4 + (t >> 6);
            int lane = t & 63;
            const f4* r = reinterpret_cast<const f4*>(frags + (size_t)wave * VOCAB);
            float best = -1e30f;
            int bidx = 0;
            for (int i = lane; i < VOCAB / 4; i += 64) {
                f4 v = __builtin_nontemporal_load(r + i);
                int base = i * 4;
                if (v.x > best) { best = v.x; bidx = base + 0; }
                if (v.y > best) { best = v.y; bidx = base + 1; }
                if (v.z > best) { best = v.z; bidx = base + 2; }
                if (v.w > best) { best = v.w; bidx = base + 3; }
            }
            for (int off = 32; off > 0; off >>= 1) {
                float ov = __shfl_xor(best, off, 64);
                int   oi = __shfl_xor(bidx, off, 64);
                if (ov > best || (ov == best && oi < bidx)) { best = ov; bidx = oi; }
            }
            if (lane == 0) frag_id[wave] = bidx;
        } else {
            // ---- cvt block (logical 0..12499)
            int blk = bb >> 1;
            size_t i = (size_t)blk * 256 + t;
            const f4* xp = reinterpret_cast<const f4*>(x);
            f4 v0 = __builtin_nontemporal_load(xp + 2 * i);
            f4 v1 = __builtin_nontemporal_load(xp + 2 * i + 1);
            uint4 o;
            o.x = (unsigned)f2bf(v0.x) | ((unsigned)f2bf(v0.y) << 16);
            o.y = (unsigned)f2bf(v0.z) | ((unsigned)f2bf(v0.w) << 16);
            o.z = (unsigned)f2bf(v1.x) | ((unsigned)f2bf(v1.y) << 16);
            o.w = (unsigned)f2bf(v1.z) | ((unsigned)f2bf(v1.w) << 16);
            *reinterpret_cast<uint4*>(xb + i * 8) = o;
        }
    } else if (bb < 25391) {
        int i = (bb - 25000) * 256 + t;
        if (i < 100000) {
            int4 r4 = reinterpret_cast<const int4*>(row)[i];
            int4 c4 = reinterpret_cast<const int4*>(col)[i];
            atomicAdd(&cnt[F + r4.x], 1); atomicAdd(&cnt[F + r4.y], 1);
            atomicAdd(&cnt[F + r4.z], 1); atomicAdd(&cnt[F + r4.w], 1);
            atomicAdd(&cnt[c4.x], 1); atomicAdd(&cnt[c4.y], 1);
            atomicAdd(&cnt[c4.z], 1); atomicAdd(&cnt[c4.w], 1);
        }
    } else {
        int bp = bb - 25391;         // 0..400
        int j = t & 127, half = t >> 7;
        if (bp < 400) {
            int v = bp * 2 + half;
            e[half][j] = emb[(size_t)v * HDIM + j];
            __syncthreads();
            float a = 0.f;
            for (int k = 0; k < HDIM; ++k)
                a = fmaf(e[half][k], W_f[k * HDIM + j], a);
            t1[half][j] = a;
            __syncthreads();
            float bbv = 0.f;
            for (int k = 0; k < HDIM; ++k)
                bbv = fmaf(t1[half][k], W_s[(HDIM + k) * HDIM + j], bbv);
            E2[(size_t)v * HDIM + j] = bbv;
        } else {
            if (half == 0) e[0][j] = b_f[j];
            __syncthreads();
            if (half == 0) {
                float bbv = b_s[j];
                for (int k = 0; k < HDIM; ++k)
                    bbv = fmaf(e[0][k], W_s[(HDIM + k) * HDIM + j], bbv);
                bfs[j] = bbv;
            }
        }
    }
}

// ---------- per-256-block sums over concatenated cnt (L = F+N)
__global__ void k_bsum(const int* __restrict__ cnt, int L, int* __restrict__ bsum) {
    __shared__ int s[256];
    int t = threadIdx.x;
    int i = blockIdx.x * 256 + t;
    s[t] = (i < L) ? cnt[i] : 0;
    __syncthreads();
    for (int o = 128; o > 0; o >>= 1) {
        if (t < o) s[t] += s[t + o];
        __syncthreads();
    }
    if (t == 0) bsum[blockIdx.x] = s[0];
}

// ---------- exclusive scan of block sums (nb <= 1024), single block
__global__ void k_scan(int* __restrict__ bsum, int nb) {
    __shared__ int s[1024];
    int t = threadIdx.x;
    int v = (t < nb) ? bsum[t] : 0;
    s[t] = v;
    __syncthreads();
    for (int o = 1; o < 1024; o <<= 1) {
        int a = (t >= o) ? s[t - o] : 0;
        __syncthreads();
        s[t] += a;
        __syncthreads();
    }
    if (t < nb) bsum[t] = s[t] - v;
}

// ---------- base[i] = bsum[block] + in-block exclusive scan
__global__ void k_base(const int* __restrict__ cnt, const int* __restrict__ bsum, int L,
                       int* __restrict__ base) {
    __shared__ int s[256];
    int t = threadIdx.x;
    int i = blockIdx.x * 256 + t;
    int v = (i < L) ? cnt[i] : 0;
    s[t] = v;
    __syncthreads();
    for (int o = 1; o < 256; o <<= 1) {
        int a = (t >= o) ? s[t - o] : 0;
        __syncthreads();
        s[t] += a;
        __syncthreads();
    }
    if (i < L) base[i] = bsum[blockIdx.x] + s[t] - v;
}

// ---------- place edges into concatenated CSR; cursor IS base
__global__ void k_place(const int* __restrict__ row, const int* __restrict__ col,
                        int* __restrict__ base, int* __restrict__ pay, int F, int E) {
    int i = blockIdx.x * 256 + threadIdx.x;
    if (i >= E / 4) return;
    int4 r4 = reinterpret_cast<const int4*>(row)[i];
    int4 c4 = reinterpret_cast<const int4*>(col)[i];
#define PL(r, c) { \
    int pc = atomicAdd(&base[c], 1); pay[pc] = r; \
    int pr = atomicAdd(&base[F + r], 1); pay[pr] = c; }
    PL(r4.x, c4.x) PL(r4.y, c4.y) PL(r4.z, c4.z) PL(r4.w, c4.w)
#undef PL
}

// ---------- fragment pool (bf16 xb gather, uint4/16-lane rows, 3-deep) + packed matvec
__global__ __launch_bounds__(256) void k_frag(
        const unsigned short* __restrict__ xb, const int* __restrict__ base,
        const int* __restrict__ pay, const int* __restrict__ frag_id,
        const float* __restrict__ W_s, const float* __restrict__ E2,
        const float* __restrict__ bfs, unsigned short* __restrict__ fembb, int F, int E) {
    __shared__ f2 sI[FB / 2][HDIM];   // fragment PAIRS interleaved
    __shared__ int eidx[TILE];
    __shared__ int cb[FB + 1];
    int t = threadIdx.x;
    int sg = t >> 4, l = t & 15;      // 16 sub-groups x 16 lanes; lane covers dims 8l..8l+7
    int fb = blockIdx.x * FB;
    if (t <= FB) {
        int idx = fb + t - 1;
        cb[t] = (idx < 0) ? 0 : ((idx < F) ? base[idx] : E);
    }
    __syncthreads();
    int st0 = cb[sg],      d0 = cb[sg + 1] - st0;
    int st1 = cb[16 + sg], d1 = cb[17 + sg] - st1;
    int p0 = cb[0], pend = cb[FB];
    const uint4* x4 = reinterpret_cast<const uint4*>(xb);   // row = 16 uint4
    float4 z = make_float4(0.f, 0.f, 0.f, 0.f);
    float4 a0A0 = z, a0A1 = z, a0B0 = z, a0B1 = z, a0C0 = z, a0C1 = z;
    float4 a1A0 = z, a1A1 = z, a1B0 = z, a1B1 = z, a1C0 = z, a1C1 = z;
    for (int tb = p0; tb < pend; tb += TILE) {
        int nload = min(TILE, pend - tb);
        for (int i = t; i < nload; i += 256) eidx[i] = pay[tb + i];
        __syncthreads();
        int lim = tb + nload;
        int lo0 = max(st0, tb) - tb, hi0 = min(st0 + d0, lim) - tb;
        int lo1 = max(st1, tb) - tb, hi1 = min(st1 + d1, lim) - tb;
        int m = max(hi0 - lo0, hi1 - lo1);
        for (int j = 0; j < m; j += 3) {
            if (lo0 + j < hi0)     { uint4 h = x4[(size_t)eidx[lo0 + j]     * 16 + l]; ACC8(a0A0, a0A1, h); }
            if (lo0 + j + 1 < hi0) { uint4 h = x4[(size_t)eidx[lo0 + j + 1] * 16 + l]; ACC8(a0B0, a0B1, h); }
            if (lo0 + j + 2 < hi0) { uint4 h = x4[(size_t)eidx[lo0 + j + 2] * 16 + l]; ACC8(a0C0, a0C1, h); }
            if (lo1 + j < hi1)     { uint4 h = x4[(size_t)eidx[lo1 + j]     * 16 + l]; ACC8(a1A0, a1A1, h); }
            if (lo1 + j + 1 < hi1) { uint4 h = x4[(size_t)eidx[lo1 + j + 1] * 16 + l]; ACC8(a1B0, a1B1, h); }
            if (lo1 + j + 2 < hi1) { uint4 h = x4[(size_t)eidx[lo1 + j + 2] * 16 + l]; ACC8(a1C0, a1C1, h); }
        }
        __syncthreads();
    }
    {
        float inv0 = 1.0f / fmaxf((float)d0, 1.0f);
        float inv1 = 1.0f / fmaxf((float)d1, 1.0f);
        int pr0 = sg >> 1, pa0 = sg & 1;
        int pr1 = (16 + sg) >> 1, pa1 = sg & 1;
        float v0[8] = { (a0A0.x + a0B0.x + a0C0.x) * inv0, (a0A0.y + a0B0.y + a0C0.y) * inv0,
                        (a0A0.z + a0B0.z + a0C0.z) * inv0, (a0A0.w + a0B0.w + a0C0.w) * inv0,
                        (a0A1.x + a0B1.x + a0C1.x) * inv0, (a0A1.y + a0B1.y + a0C1.y) * inv0,
                        (a0A1.z + a0B1.z + a0C1.z) * inv0, (a0A1.w + a0B1.w + a0C1.w) * inv0 };
        float v1[8] = { (a1A0.x + a1B0.x + a1C0.x) * inv1, (a1A0.y + a1B0.y + a1C0.y) * inv1,
                        (a1A0.z + a1B0.z + a1C0.z) * inv1, (a1A0.w + a1B0.w + a1C0.w) * inv1,
                        (a1A1.x + a1B1.x + a1C1.x) * inv1, (a1A1.y + a1B1.y + a1C1.y) * inv1,
                        (a1A1.z + a1B1.z + a1C1.z) * inv1, (a1A1.w + a1B1.w + a1C1.w) * inv1 };
#pragma unroll
        for (int i = 0; i < 8; ++i) {
            ((float*)&sI[pr0][8 * l + i])[pa0] = v0[i];
            ((float*)&sI[pr1][8 * l + i])[pa1] = v1[i];
        }
    }
    __syncthreads();
    // matvec: thread = dim d; half fh handles 8 fragment-pairs (16 frags)
    int d = t & 127;
    int fh = t >> 7;
    float bv = bfs[d];
    f2 acc2[8];
#pragma unroll
    for (int q = 0; q < 8; ++q) {
        int pr = fh * 8 + q;
        int fA = fb + 2 * pr, fB = fA + 1;
        int idA = frag_id[min(fA, F - 1)];
        int idB = frag_id[min(fB, F - 1)];
        acc2[q].x = E2[(size_t)idA * HDIM + d] + bv;
        acc2[q].y = E2[(size_t)idB * HDIM + d] + bv;
    }
    for (int k = 0; k < HDIM; k += 2) {
        float w0 = W_s[(k + 0) * HDIM + d];
        float w1 = W_s[(k + 1) * HDIM + d];
        f2 w0v; w0v.x = w0; w0v.y = w0;
        f2 w1v; w1v.x = w1; w1v.y = w1;
#pragma unroll
        for (int q = 0; q < 8; ++q) {
            int pr = fh * 8 + q;
            f2 vv0 = sI[pr][k];
            f2 vv1 = sI[pr][k + 1];
            acc2[q] += vv0 * w0v + vv1 * w1v;
        }
    }
#pragma unroll
    for (int q = 0; q < 8; ++q) {
        int pr = fh * 8 + q;
        int fA = fb + 2 * pr;
        if (fA < F)     fembb[(size_t)fA * HDIM + d]       = f2bf(acc2[q].x);
        if (fA + 1 < F) fembb[(size_t)(fA + 1) * HDIM + d] = f2bf(acc2[q].y);
    }
}

// ---------- node pool + divide; bf16 femb gather (uint4/16-lane rows), nt out stores
__global__ __launch_bounds__(256) void k_node(
        const unsigned short* __restrict__ fembb, const int* __restrict__ base,
        const int* __restrict__ pay, float* __restrict__ out, int F, int E, int N) {
    __shared__ int eidx[TILE_N];
    __shared__ int cb[NB + 1];
    int t = threadIdx.x;
    int sg = t >> 4, l = t & 15;      // 16 sub-groups; lane covers dims 8l..8l+7
    int n0 = blockIdx.x * NB;
    if (t <= NB) {
        int idx = n0 + t - 1;
        cb[t] = (idx < 0) ? E : base[F + idx];   // row region starts at E in pay
    }
    __syncthreads();
    int st_[4], dg_[4];
    float4 z = make_float4(0.f, 0.f, 0.f, 0.f);
    float4 aA0[4] = {z, z, z, z}, aA1[4] = {z, z, z, z};
    float4 aB0[4] = {z, z, z, z}, aB1[4] = {z, z, z, z};
#pragma unroll
    for (int q = 0; q < 4; ++q) {
        st_[q] = cb[sg * 4 + q];
        dg_[q] = cb[sg * 4 + q + 1] - st_[q];
    }
    int p0 = cb[0], pend = cb[NB];
    const uint4* f4p = reinterpret_cast<const uint4*>(fembb);
    for (int tb = p0; tb < pend; tb += TILE_N) {
        int nload = min(TILE_N, pend - tb);
        for (int i = t; i < nload; i += 256) eidx[i] = pay[tb + i];
        __syncthreads();
        int lim = tb + nload;
        int lo[4], hi[4];
        int m = 0;
#pragma unroll
        for (int q = 0; q < 4; ++q) {
            lo[q] = max(st_[q], tb) - tb;
            hi[q] = min(st_[q] + dg_[q], lim) - tb;
            m = max(m, hi[q] - lo[q]);
        }
        for (int j = 0; j < m; j += 2) {
#pragma unroll
            for (int q = 0; q < 4; ++q) {
                if (lo[q] + j < hi[q])     { uint4 h = f4p[(size_t)eidx[lo[q] + j]     * 16 + l]; ACC8(aA0[q], aA1[q], h); }
                if (lo[q] + j + 1 < hi[q]) { uint4 h = f4p[(size_t)eidx[lo[q] + j + 1] * 16 + l]; ACC8(aB0[q], aB1[q], h); }
            }
        }
        __syncthreads();
    }
    f4* o4 = reinterpret_cast<f4*>(out);
#pragma unroll
    for (int q = 0; q < 4; ++q) {
        float inv = 1.0f / fmaxf((float)dg_[q], 1.0f);
        f4 w0, w1;
        w0.x = (aA0[q].x + aB0[q].x) * inv; w0.y = (aA0[q].y + aB0[q].y) * inv;
        w0.z = (aA0[q].z + aB0[q].z) * inv; w0.w = (aA0[q].w + aB0[q].w) * inv;
        w1.x = (aA1[q].x + aB1[q].x) * inv; w1.y = (aA1[q].y + aB1[q].y) * inv;
        w1.z = (aA1[q].z + aB1[q].z) * inv; w1.w = (aA1[q].w + aB1[q].w) * inv;
        size_t nrow = (size_t)(n0 + sg * 4 + q) * 32;
        __builtin_nontemporal_store(w0, o4 + nrow + 2 * l + 0);
        __builtin_nontemporal_store(w1, o4 + nrow + 2 * l + 1);
    }
}

extern "C" void kernel_launch(void* const* d_in, const int* in_sizes, int n_in,
                              void* d_out, int out_size, void* d_ws, size_t ws_size,
                              hipStream_t stream) {
    const float* x         = (const float*)d_in[0];
    const float* fragments = (const float*)d_in[1];
    const float* emb_table = (const float*)d_in[2];
    const float* W_f       = (const float*)d_in[3];
    const float* b_f       = (const float*)d_in[4];
    const float* W_s       = (const float*)d_in[5];
    const float* b_s       = (const float*)d_in[6];
    const int*   row       = (const int*)d_in[7];
    const int*   col       = (const int*)d_in[8];
    float* out = (float*)d_out;

    const int N = 200000, F = 50000, E = 400000;
    const int L = F + N;                 // concatenated CSR domain
    const int NBT = (L + 255) / 256;     // 977

    // xb (bf16 x, 51.2 MB) lives in d_out: fully dead before k_node overwrites out.
    unsigned short* xb = (unsigned short*)d_out;

    unsigned short* fembb = (unsigned short*)d_ws;     // F*128 bf16 = 12.8 MB
    int* cnt     = (int*)(fembb + (size_t)F * HDIM);   // L   (cols at 0, rows at F)
    int* base    = cnt + L;                            // L
    int* bsum    = base + L;                           // 1024
    int* pay     = bsum + 1024;                        // 2E  (col CSR at 0, row CSR at E)
    int* frag_id = pay + 2 * E;                        // F
    float* E2    = (float*)(frag_id + F);              // VOCAB*128
    float* bfs   = E2 + VOCAB * HDIM;                  // 128

    hipMemsetAsync(cnt, 0, (size_t)L * sizeof(int), stream);

    k_amc<<<25792, 256, 0, stream>>>(fragments, frag_id, x, xb, row, col, cnt,
                                     emb_table, W_f, W_s, b_f, b_s, E2, bfs, F);
    k_bsum<<<NBT, 256, 0, stream>>>(cnt, L, bsum);
    k_scan<<<1, 1024, 0, stream>>>(bsum, NBT);
    k_base<<<NBT, 256, 0, stream>>>(cnt, bsum, L, base);
    k_place<<<(E / 4 + 255) / 256, 256, 0, stream>>>(row, col, base, pay, F, E);
    k_frag<<<(F + FB - 1) / FB, 256, 0, stream>>>(xb, base, pay, frag_id, W_s, E2, bfs,
                                                  fembb, F, E);
    k_node<<<N / NB, 256, 0, stream>>>(fembb, base, pay, out, F, E, N);
}